// Round 4
// baseline (379.602 us; speedup 1.0000x reference)
//
#include <hip/hip_runtime.h>

#define HID    192
#define HID2   384
#define NEDGES 262144
#define MB     64
#define NBLK   (NEDGES / MB)   // 4096

// LDS map (bf16 elems), total 27648 = 55296 B -> 2 blocks/CU (512 thr, 8 waves):
//   A_src [0,12800)      64 x 200   (phase 1-2)
//   dstE  [12800,13600)   4 x 200   (phase 1-2)
//   H1    [0,26112)      64 x 408   (phase 3-4, overlays A_src+dstE)
//   dstC  [26112,27648)   4 x 384   (written P2a, read P3)
//   mh2   [26112,26944)   4 x 208   (written P5, read P6; overlays dead dstC)
#define ALD   200
#define DLD   200
#define H1LD  408
#define MLD   208
#define DSTE  12800
#define DSTC  26112
#define MH2   26112
#define SMEM_ELEMS 27648

typedef __bf16 bf16;
typedef __bf16 bv8 __attribute__((ext_vector_type(8)));
typedef __bf16 bv4 __attribute__((ext_vector_type(4)));
typedef float f32x4 __attribute__((ext_vector_type(4)));

// tanh-form gelu: x * (1 - 1/(e^{2u}+1)),  2u = 1.59577(x + 0.044715 x^3)
__device__ __forceinline__ float gelu_fast(float x) {
    float x2 = x * x;
    float u2 = 1.5957691216057308f * x * __builtin_fmaf(0.044715f, x2, 1.0f);
    float e  = __expf(u2);
    float inv = __builtin_amdgcn_rcpf(e + 1.0f);
    return __builtin_fmaf(-x, inv, x);
}

// ---- weight transpose + f32->bf16 cast: W*T[n][k] = W*[k][n] ----
__global__ void wprep_kernel(const float* __restrict__ W1, const float* __restrict__ W2,
                             const float* __restrict__ W3,
                             bf16* __restrict__ W1T, bf16* __restrict__ W2T,
                             bf16* __restrict__ W3T) {
    int idx = blockIdx.x * 256 + threadIdx.x;
    if (idx < 147456) {                 // W1: 384x384
        int n = idx / 384, k = idx - n * 384;
        W1T[idx] = (bf16)W1[k * 384 + n];
    } else if (idx < 221184) {          // W2: (384,192) -> W2T 192x384
        int j = idx - 147456;
        int n = j / 384, k = j - n * 384;
        W2T[j] = (bf16)W2[k * 192 + n];
    } else if (idx < 258048) {          // W3: (192,192) -> W3T 192x192
        int j = idx - 221184;
        int n = j / 192, k = j - n * 192;
        W3T[j] = (bf16)W3[k * 192 + n];
    }
}

__global__ __launch_bounds__(512, 4)
void fused_mlp_kernel(const float* __restrict__ pos, const int* __restrict__ edges,
                      const bf16* __restrict__ W1T, const float* __restrict__ b1,
                      const bf16* __restrict__ W2T, const float* __restrict__ b2,
                      const bf16* __restrict__ W3T, const float* __restrict__ b3,
                      float* __restrict__ out) {
    __shared__ __align__(16) bf16 smem[SMEM_ELEMS];
    const int tid  = threadIdx.x;
    const int w    = tid >> 6;          // wave 0..7
    const int lane = tid & 63;
    const int quad = lane >> 4;
    const int l15  = lane & 15;
    const int blk  = blockIdx.x;

    // ========== P1: gather A_src (64x192) + dstE (4x192), sincos on the fly ==========
    {
        const int r    = tid >> 3;          // edge row 0..63
        const int part = tid & 7;           // 8 threads/row, 24 cols each
        const int e    = blk * MB + r;
        const int node = edges[2 * e + 1];
        const float p0 = pos[node * 3 + 0];
        const float p1 = pos[node * 3 + 1];
        const float p2 = pos[node * 3 + 2];
        bf16* ldst = smem + r * ALD + part * 24;
        #pragma unroll
        for (int g = 0; g < 3; ++g) {
            const int t0    = part * 24 + g * 8;     // 8-aligned -> dim/isCos uniform
            const int dim   = t0 >> 6;
            const int isCos = t0 & 32;
            const int f0    = t0 & 31;
            const float pv  = (dim == 0) ? p0 : ((dim == 1) ? p1 : p2);
            float om = exp2f(-0.4152410118609203f * (float)f0);  // 10000^(-f0/32)
            bv8 v;
            #pragma unroll
            for (int j = 0; j < 8; ++j) {
                const float x = pv * om;
                v[j] = (bf16)(isCos ? __cosf(x) : __sinf(x));
                om *= 0.74989420933245582f;                      // 10000^(-1/32)
            }
            *reinterpret_cast<bv8*>(ldst + g * 8) = v;
        }
    }
    if (tid < 192) {   // dstE: 4 segment rows x 192
        const int s    = tid / 48;
        const int c0   = (tid - s * 48) * 4;
        const int node = edges[2 * (blk * MB + s * 16)];
        const int dim  = c0 >> 6;
        const int isCos = c0 & 32;
        const int f0   = c0 & 31;
        const float pv = pos[node * 3 + dim];
        float om = exp2f(-0.4152410118609203f * (float)f0);
        bv4 v;
        #pragma unroll
        for (int j = 0; j < 4; ++j) {
            const float x = pv * om;
            v[j] = (bf16)(isCos ? __cosf(x) : __sinf(x));
            om *= 0.74989420933245582f;
        }
        *reinterpret_cast<bv4*>(smem + DSTE + s * DLD + c0) = v;
    }
    __syncthreads();   // b1

    const f32x4 fz = {0.f, 0.f, 0.f, 0.f};

    // ========== P2a: mini-GEMM (swapped) dstC = dstE @ W1[192:384], -> LDS ==========
    {
        f32x4 accd[3];
        #pragma unroll
        for (int mc = 0; mc < 3; ++mc) accd[mc] = fz;
        const bf16* wb = W1T + (size_t)(w * 48 + l15) * HID2 + 192 + quad * 8;
        const bf16* db = smem + DSTE + (l15 & 3) * DLD + quad * 8;
        for (int kt = 0; kt < 6; ++kt) {
            bv8 bfrag = *reinterpret_cast<const bv8*>(db + kt * 32);
            #pragma unroll
            for (int mc = 0; mc < 3; ++mc) {
                bv8 afrag = *reinterpret_cast<const bv8*>(wb + mc * 16 * HID2 + kt * 32);
                accd[mc] = __builtin_amdgcn_mfma_f32_16x16x32_bf16(afrag, bfrag, accd[mc], 0, 0, 0);
            }
        }
        // D[outcol=quad*4+r][dstrow=l15]; lanes l15<4 hold distinct rows -> b64 stores
        if (l15 < 4) {
            #pragma unroll
            for (int mc = 0; mc < 3; ++mc) {
                bv4 pk;
                #pragma unroll
                for (int r = 0; r < 4; ++r) pk[r] = (bf16)accd[mc][r];
                *reinterpret_cast<bv4*>(smem + DSTC + l15 * HID2 + w * 48 + mc * 16 + quad * 4) = pk;
            }
        }
    }

    // ========== P2b: GEMM1 (swapped) acc1[outcol-tile][edge-tile], K=192 ==========
    f32x4 acc1[3][4];
    #pragma unroll
    for (int mc = 0; mc < 3; ++mc)
        #pragma unroll
        for (int ne = 0; ne < 4; ++ne) acc1[mc][ne] = fz;
    {
        const bf16* wb = W1T + (size_t)(w * 48 + l15) * HID2 + quad * 8;
        const bf16* xb = smem + l15 * ALD + quad * 8;
        for (int kt = 0; kt < 6; ++kt) {
            bv8 x[4];
            #pragma unroll
            for (int ne = 0; ne < 4; ++ne)
                x[ne] = *reinterpret_cast<const bv8*>(xb + ne * 16 * ALD + kt * 32);
            #pragma unroll
            for (int mc = 0; mc < 3; ++mc) {
                bv8 a = *reinterpret_cast<const bv8*>(wb + mc * 16 * HID2 + kt * 32);
                #pragma unroll
                for (int ne = 0; ne < 4; ++ne)
                    acc1[mc][ne] = __builtin_amdgcn_mfma_f32_16x16x32_bf16(a, x[ne], acc1[mc][ne], 0, 0, 0);
            }
        }
    }
    __syncthreads();   // b2: A_src/dstE dead, dstC visible

    // ========== P3: epilogue -> H1 = gelu(src + dstC + b1), b64 stores ==========
    {
        const int cb = w * 48 + quad * 4;
        #pragma unroll
        for (int mc = 0; mc < 3; ++mc) {
            f32x4 bia = *reinterpret_cast<const f32x4*>(b1 + cb + mc * 16);
            #pragma unroll
            for (int ne = 0; ne < 4; ++ne) {
                bv4 dc = *reinterpret_cast<const bv4*>(smem + DSTC + ne * HID2 + cb + mc * 16);
                bv4 o;
                #pragma unroll
                for (int r = 0; r < 4; ++r)
                    o[r] = (bf16)gelu_fast(acc1[mc][ne][r] + (float)dc[r] + bia[r]);
                *reinterpret_cast<bv4*>(smem + (ne * 16 + l15) * H1LD + cb + mc * 16) = o;
            }
        }
    }
    __syncthreads();   // b3: H1 complete

    // ========== P4: GEMM2 (normal), wave covers (mgrp: 32 edges) x (ncb: 48 cols) ==========
    const int mgrp = w >> 2;
    const int ncb  = (w & 3) * 3;
    f32x4 acc2[2][3];
    #pragma unroll
    for (int m = 0; m < 2; ++m)
        #pragma unroll
        for (int nc = 0; nc < 3; ++nc) acc2[m][nc] = fz;
    {
        const bf16* hb = smem + (mgrp * 32 + l15) * H1LD + quad * 8;
        const bf16* wb = W2T + (size_t)(ncb * 16 + l15) * HID2 + quad * 8;
        for (int kt = 0; kt < 12; ++kt) {
            bv8 h[2];
            #pragma unroll
            for (int m = 0; m < 2; ++m)
                h[m] = *reinterpret_cast<const bv8*>(hb + m * 16 * H1LD + kt * 32);
            #pragma unroll
            for (int nc = 0; nc < 3; ++nc) {
                bv8 b = *reinterpret_cast<const bv8*>(wb + nc * 16 * HID2 + kt * 32);
                #pragma unroll
                for (int m = 0; m < 2; ++m)
                    acc2[m][nc] = __builtin_amdgcn_mfma_f32_16x16x32_bf16(h[m], b, acc2[m][nc], 0, 0, 0);
            }
        }
    }
    // ========== P5: gelu2 + segment mean -> mh2 ==========
    #pragma unroll
    for (int nc = 0; nc < 3; ++nc) {
        const int colv = (ncb + nc) * 16 + l15;
        const float bia = b2[colv];
        #pragma unroll
        for (int m = 0; m < 2; ++m) {
            float s = gelu_fast(acc2[m][nc][0] + bia) + gelu_fast(acc2[m][nc][1] + bia)
                    + gelu_fast(acc2[m][nc][2] + bia) + gelu_fast(acc2[m][nc][3] + bia);
            s += __shfl_xor(s, 16);
            s += __shfl_xor(s, 32);
            if (quad == 0)
                smem[MH2 + (mgrp * 2 + m) * MLD + colv] = (bf16)(s * 0.0625f);
        }
    }
    __syncthreads();   // b4: mh2 complete

    // ========== P6: GEMM3 on means (waves 0-3), + b3 ==========
    if (w < 4) {
        f32x4 acc3[3];
        #pragma unroll
        for (int nc = 0; nc < 3; ++nc) acc3[nc] = fz;
        const bf16* ab = smem + MH2 + (l15 & 3) * MLD + quad * 8;
        const bf16* wb = W3T + (size_t)(w * 48 + l15) * HID + quad * 8;
        for (int kt = 0; kt < 6; ++kt) {
            bv8 a = *reinterpret_cast<const bv8*>(ab + kt * 32);
            #pragma unroll
            for (int nc = 0; nc < 3; ++nc) {
                bv8 b = *reinterpret_cast<const bv8*>(wb + nc * 16 * HID + kt * 32);
                acc3[nc] = __builtin_amdgcn_mfma_f32_16x16x32_bf16(a, b, acc3[nc], 0, 0, 0);
            }
        }
        if (quad == 0) {
            #pragma unroll
            for (int nc = 0; nc < 3; ++nc) {
                const int col   = (w * 3 + nc) * 16 + l15;
                const float bia = b3[col];
                #pragma unroll
                for (int r = 0; r < 4; ++r)   // C row r (quad 0) == segment r
                    out[(size_t)(blk * 4 + r) * HID + col] = acc3[nc][r] + bia;
            }
        }
    }
}

extern "C" void kernel_launch(void* const* d_in, const int* in_sizes, int n_in,
                              void* d_out, int out_size, void* d_ws, size_t ws_size,
                              hipStream_t stream) {
    const float* mesh_pos = (const float*)d_in[0];
    const int*   edges    = (const int*)  d_in[1];
    // d_in[2] = batch_idx (unused)
    const float* W1 = (const float*)d_in[3];
    const float* b1 = (const float*)d_in[4];
    const float* W2 = (const float*)d_in[5];
    const float* b2 = (const float*)d_in[6];
    const float* W3 = (const float*)d_in[7];
    const float* b3 = (const float*)d_in[8];
    float* out = (float*)d_out;

    bf16* W1T = (bf16*)d_ws;            // 516 KB total in ws
    bf16* W2T = W1T + 147456;
    bf16* W3T = W2T + 73728;

    wprep_kernel<<<(258048 + 255) / 256, 256, 0, stream>>>(W1, W2, W3, W1T, W2T, W3T);
    fused_mlp_kernel<<<NBLK, 512, 0, stream>>>(mesh_pos, edges, W1T, b1, W2T, b2, W3T, b3, out);
}

// Round 5
// 274.869 us; speedup vs baseline: 1.3810x; 1.3810x over previous
//
#include <hip/hip_runtime.h>

#define HID    192
#define HID2   384
#define NEDGES 262144
#define NSEG   16384
#define MB     64
#define NBLK   (NEDGES / MB)   // 4096

#define ALD   200              // embed-tile LDS row stride (bf16 elems)
#define H1LD  408              // H1 LDS row stride
#define SMEM2 26112            // 64*408 bf16 = 52224 B -> 3 blocks/CU

typedef __bf16 bf16;
typedef __bf16 bv8 __attribute__((ext_vector_type(8)));
typedef __bf16 bv4 __attribute__((ext_vector_type(4)));
typedef float f32x4 __attribute__((ext_vector_type(4)));

__device__ __forceinline__ float gelu_fast(float x) {
    float x2 = x * x;
    float u2 = 1.5957691216057308f * x * __builtin_fmaf(0.044715f, x2, 1.0f);
    float e  = __expf(u2);
    float inv = __builtin_amdgcn_rcpf(e + 1.0f);
    return __builtin_fmaf(-x, inv, x);
}

// sincos embed for one node, 8 cols starting at t0 (t0 % 8 == 0)
__device__ __forceinline__ bv8 embed8(float p0, float p1, float p2, int t0) {
    const int dim   = t0 >> 6;
    const int isCos = t0 & 32;
    const int f0    = t0 & 31;
    const float pv  = (dim == 0) ? p0 : ((dim == 1) ? p1 : p2);
    float om = exp2f(-0.4152410118609203f * (float)f0);   // 10000^(-f0/32)
    bv8 v;
    #pragma unroll
    for (int j = 0; j < 8; ++j) {
        const float x = pv * om;
        v[j] = (bf16)(isCos ? __cosf(x) : __sinf(x));
        om *= 0.74989420933245582f;                       // 10000^(-1/32)
    }
    return v;
}

// ---- K0: tiled transpose + cast. S is KxN f32, D = S^T (NxK) bf16 ----
__global__ void wprep_kernel(const float* __restrict__ W1, const float* __restrict__ W2,
                             const float* __restrict__ W3,
                             bf16* __restrict__ W1T, bf16* __restrict__ W2T,
                             bf16* __restrict__ W3T) {
    __shared__ float t[32][33];
    int b = blockIdx.x;
    const float* S; bf16* D; int K, N, tk, tn;
    if (b < 144)      { S = W1; D = W1T; K = 384; N = 384; tk = (b / 12) * 32; tn = (b % 12) * 32; }
    else if (b < 216) { b -= 144; S = W2; D = W2T; K = 384; N = 192; tk = (b / 6) * 32; tn = (b % 6) * 32; }
    else              { b -= 216; S = W3; D = W3T; K = 192; N = 192; tk = (b / 6) * 32; tn = (b % 6) * 32; }
    const int c = threadIdx.x & 31, r0 = threadIdx.x >> 5;
    #pragma unroll
    for (int i = 0; i < 4; ++i)
        t[r0 + i * 8][c] = S[(size_t)(tk + r0 + i * 8) * N + tn + c];
    __syncthreads();
    #pragma unroll
    for (int i = 0; i < 4; ++i)
        D[(size_t)(tn + r0 + i * 8) * K + tk + c] = (bf16)t[c][r0 + i * 8];
}

// ---- K1: dstC[seg][0:384] = embed(dst_node(seg)) @ W1[192:384,:]  (M=16384) ----
// 64 segs/block, 256 blocks, 4 waves, swapped MFMA (A=weights).
__global__ __launch_bounds__(256, 3)
void dstc_kernel(const float* __restrict__ pos, const int* __restrict__ edges,
                 const bf16* __restrict__ W1T, bf16* __restrict__ dstC) {
    __shared__ __align__(16) bf16 smem[MB * ALD];
    const int tid = threadIdx.x, w = tid >> 6, lane = tid & 63;
    const int quad = lane >> 4, l15 = lane & 15, blk = blockIdx.x;
    {
        const int r = tid >> 2, part = tid & 3;            // 4 thr/row, 48 cols
        const int node = edges[2 * ((blk * MB + r) * 16)]; // dst node of segment
        const float p0 = pos[node * 3 + 0], p1 = pos[node * 3 + 1], p2 = pos[node * 3 + 2];
        bf16* ldst = smem + r * ALD + part * 48;
        #pragma unroll
        for (int g = 0; g < 6; ++g)
            *reinterpret_cast<bv8*>(ldst + g * 8) = embed8(p0, p1, p2, part * 48 + g * 8);
    }
    __syncthreads();
    const f32x4 fz = {0.f, 0.f, 0.f, 0.f};
    f32x4 acc[6][4];
    #pragma unroll
    for (int mc = 0; mc < 6; ++mc)
        #pragma unroll
        for (int ne = 0; ne < 4; ++ne) acc[mc][ne] = fz;
    const bf16* wb = W1T + (size_t)(w * 96 + l15) * HID2 + 192 + quad * 8;  // dst half
    const bf16* xb = smem + l15 * ALD + quad * 8;
    for (int kt = 0; kt < 6; ++kt) {
        bv8 x[4];
        #pragma unroll
        for (int ne = 0; ne < 4; ++ne)
            x[ne] = *reinterpret_cast<const bv8*>(xb + ne * 16 * ALD + kt * 32);
        #pragma unroll
        for (int mc = 0; mc < 6; ++mc) {
            bv8 a = *reinterpret_cast<const bv8*>(wb + mc * 16 * HID2 + kt * 32);
            #pragma unroll
            for (int ne = 0; ne < 4; ++ne)
                acc[mc][ne] = __builtin_amdgcn_mfma_f32_16x16x32_bf16(a, x[ne], acc[mc][ne], 0, 0, 0);
        }
    }
    // D[outcol=quad*4+r][segrow=l15]: b64 stores, 4 consecutive cols
    #pragma unroll
    for (int mc = 0; mc < 6; ++mc)
        #pragma unroll
        for (int ne = 0; ne < 4; ++ne) {
            bv4 pk;
            #pragma unroll
            for (int r = 0; r < 4; ++r) pk[r] = (bf16)acc[mc][ne][r];
            *reinterpret_cast<bv4*>(dstC + (size_t)(blk * MB + ne * 16 + l15) * HID2
                                    + w * 96 + mc * 16 + quad * 4) = pk;
        }
}

// ---- K2: fused embed(src) -> GEMM1src -> +dstC+gelu -> GEMM2 -> gelu+mean -> mh2 ----
__global__ __launch_bounds__(256, 3)
void fused_mlp_kernel(const float* __restrict__ pos, const int* __restrict__ edges,
                      const bf16* __restrict__ W1T, const float* __restrict__ b1,
                      const bf16* __restrict__ W2T, const float* __restrict__ b2,
                      const bf16* __restrict__ dstC, bf16* __restrict__ mh2) {
    __shared__ __align__(16) bf16 smem[SMEM2];
    const int tid = threadIdx.x, w = tid >> 6, lane = tid & 63;
    const int quad = lane >> 4, l15 = lane & 15, blk = blockIdx.x;

    // P1: A_src = embed(src) 64x192 into LDS (rows stride ALD, region [0,12800))
    {
        const int r = tid >> 2, part = tid & 3;
        const int node = edges[2 * (blk * MB + r) + 1];
        const float p0 = pos[node * 3 + 0], p1 = pos[node * 3 + 1], p2 = pos[node * 3 + 2];
        bf16* ldst = smem + r * ALD + part * 48;
        #pragma unroll
        for (int g = 0; g < 6; ++g)
            *reinterpret_cast<bv8*>(ldst + g * 8) = embed8(p0, p1, p2, part * 48 + g * 8);
    }
    __syncthreads();   // b1

    const f32x4 fz = {0.f, 0.f, 0.f, 0.f};

    // P2: GEMM1 src part, swapped (A=W1T rows = outcols), K=192. acc[mc][ne]
    f32x4 acc1[6][4];
    #pragma unroll
    for (int mc = 0; mc < 6; ++mc)
        #pragma unroll
        for (int ne = 0; ne < 4; ++ne) acc1[mc][ne] = fz;
    {
        const bf16* wb = W1T + (size_t)(w * 96 + l15) * HID2 + quad * 8;
        const bf16* xb = smem + l15 * ALD + quad * 8;
        for (int kt = 0; kt < 6; ++kt) {
            bv8 x[4];
            #pragma unroll
            for (int ne = 0; ne < 4; ++ne)
                x[ne] = *reinterpret_cast<const bv8*>(xb + ne * 16 * ALD + kt * 32);
            #pragma unroll
            for (int mc = 0; mc < 6; ++mc) {
                bv8 a = *reinterpret_cast<const bv8*>(wb + mc * 16 * HID2 + kt * 32);
                #pragma unroll
                for (int ne = 0; ne < 4; ++ne)
                    acc1[mc][ne] = __builtin_amdgcn_mfma_f32_16x16x32_bf16(a, x[ne], acc1[mc][ne], 0, 0, 0);
            }
        }
    }
    __syncthreads();   // b2: A dead (H1 overlays it)

    // P3: H1 = gelu(acc1 + dstC[seg] + b1), b64 LDS stores
    {
        const int cb = w * 96 + quad * 4;
        #pragma unroll
        for (int mc = 0; mc < 6; ++mc) {
            f32x4 bia = *reinterpret_cast<const f32x4*>(b1 + cb + mc * 16);
            #pragma unroll
            for (int ne = 0; ne < 4; ++ne) {
                bv4 dc = *reinterpret_cast<const bv4*>(dstC + (size_t)(blk * 4 + ne) * HID2 + cb + mc * 16);
                bv4 o;
                #pragma unroll
                for (int r = 0; r < 4; ++r)
                    o[r] = (bf16)gelu_fast(acc1[mc][ne][r] + (float)dc[r] + bia[r]);
                *reinterpret_cast<bv4*>(smem + (ne * 16 + l15) * H1LD + cb + mc * 16) = o;
            }
        }
    }
    __syncthreads();   // b3: H1 complete

    // P4: GEMM2 normal (A=H1 rows, B=W2T), K=384, wave covers 48 N-cols
    f32x4 acc2[4][3];
    #pragma unroll
    for (int m = 0; m < 4; ++m)
        #pragma unroll
        for (int nc = 0; nc < 3; ++nc) acc2[m][nc] = fz;
    {
        const bf16* hb = smem + l15 * H1LD + quad * 8;
        const bf16* wb = W2T + (size_t)(w * 48 + l15) * HID2 + quad * 8;
        for (int kt = 0; kt < 12; ++kt) {
            bv8 h[4];
            #pragma unroll
            for (int m = 0; m < 4; ++m)
                h[m] = *reinterpret_cast<const bv8*>(hb + m * 16 * H1LD + kt * 32);
            #pragma unroll
            for (int nc = 0; nc < 3; ++nc) {
                bv8 b = *reinterpret_cast<const bv8*>(wb + nc * 16 * HID2 + kt * 32);
                #pragma unroll
                for (int m = 0; m < 4; ++m)
                    acc2[m][nc] = __builtin_amdgcn_mfma_f32_16x16x32_bf16(h[m], b, acc2[m][nc], 0, 0, 0);
            }
        }
    }

    // P5: gelu2 + segment mean (m-tile == segment) -> mh2 global
    #pragma unroll
    for (int nc = 0; nc < 3; ++nc) {
        const int colv = w * 48 + nc * 16 + l15;
        const float bia = b2[colv];
        #pragma unroll
        for (int m = 0; m < 4; ++m) {
            float s = gelu_fast(acc2[m][nc][0] + bia) + gelu_fast(acc2[m][nc][1] + bia)
                    + gelu_fast(acc2[m][nc][2] + bia) + gelu_fast(acc2[m][nc][3] + bia);
            s += __shfl_xor(s, 16);
            s += __shfl_xor(s, 32);
            if (quad == 0)
                mh2[(size_t)(blk * 4 + m) * HID + colv] = (bf16)(s * 0.0625f);
        }
    }
}

// ---- K3: out = mh2 @ W3 + b3  (M=16384, N=192, K=192), 128 segs/block ----
__global__ __launch_bounds__(256, 3)
void gemm3_kernel(const bf16* __restrict__ mh2, const bf16* __restrict__ W3T,
                  const float* __restrict__ b3, float* __restrict__ out) {
    __shared__ __align__(16) bf16 smem[128 * ALD];   // 51200 B
    const int tid = threadIdx.x, w = tid >> 6, lane = tid & 63;
    const int quad = lane >> 4, l15 = lane & 15, blk = blockIdx.x;
    {
        const int r = tid >> 1, half = tid & 1;      // 2 thr/row, 96 elems
        const bf16* src = mh2 + (size_t)(blk * 128 + r) * HID + half * 96;
        bf16* dst = smem + r * ALD + half * 96;
        #pragma unroll
        for (int i = 0; i < 12; ++i)
            reinterpret_cast<bv8*>(dst)[i] = reinterpret_cast<const bv8*>(src)[i];
    }
    __syncthreads();
    const f32x4 fz = {0.f, 0.f, 0.f, 0.f};
    f32x4 acc[8][3];
    #pragma unroll
    for (int mt = 0; mt < 8; ++mt)
        #pragma unroll
        for (int nc = 0; nc < 3; ++nc) acc[mt][nc] = fz;
    {
        const bf16* hb = smem + l15 * ALD + quad * 8;
        const bf16* wb = W3T + (size_t)(w * 48 + l15) * HID + quad * 8;
        for (int kt = 0; kt < 6; ++kt) {
            bv8 h[8];
            #pragma unroll
            for (int mt = 0; mt < 8; ++mt)
                h[mt] = *reinterpret_cast<const bv8*>(hb + mt * 16 * ALD + kt * 32);
            #pragma unroll
            for (int nc = 0; nc < 3; ++nc) {
                bv8 b = *reinterpret_cast<const bv8*>(wb + nc * 16 * HID + kt * 32);
                #pragma unroll
                for (int mt = 0; mt < 8; ++mt)
                    acc[mt][nc] = __builtin_amdgcn_mfma_f32_16x16x32_bf16(h[mt], b, acc[mt][nc], 0, 0, 0);
            }
        }
    }
    #pragma unroll
    for (int nc = 0; nc < 3; ++nc) {
        const int col = w * 48 + nc * 16 + l15;
        const float bia = b3[col];
        #pragma unroll
        for (int mt = 0; mt < 8; ++mt)
            #pragma unroll
            for (int r = 0; r < 4; ++r)
                out[(size_t)(blk * 128 + mt * 16 + quad * 4 + r) * HID + col] = acc[mt][nc][r] + bia;
    }
}

extern "C" void kernel_launch(void* const* d_in, const int* in_sizes, int n_in,
                              void* d_out, int out_size, void* d_ws, size_t ws_size,
                              hipStream_t stream) {
    const float* mesh_pos = (const float*)d_in[0];
    const int*   edges    = (const int*)  d_in[1];
    // d_in[2] = batch_idx (unused)
    const float* W1 = (const float*)d_in[3];
    const float* b1 = (const float*)d_in[4];
    const float* W2 = (const float*)d_in[5];
    const float* b2 = (const float*)d_in[6];
    const float* W3 = (const float*)d_in[7];
    const float* b3 = (const float*)d_in[8];
    float* out = (float*)d_out;

    // ws layout (bf16): W1T 147456 | W2T 73728 | W3T 36864 | dstC 16384*384 | mh2 16384*192
    bf16* W1T  = (bf16*)d_ws;
    bf16* W2T  = W1T + 147456;
    bf16* W3T  = W2T + 73728;
    bf16* dstC = W3T + 36864;
    bf16* mh2  = dstC + (size_t)NSEG * HID2;   // total ~19.4 MB

    wprep_kernel<<<252, 256, 0, stream>>>(W1, W2, W3, W1T, W2T, W3T);
    dstc_kernel<<<NSEG / MB, 256, 0, stream>>>(mesh_pos, edges, W1T, dstC);
    fused_mlp_kernel<<<NBLK, 256, 0, stream>>>(mesh_pos, edges, W1T, b1, W2T, b2, dstC, mh2);
    gemm3_kernel<<<NSEG / 128, 256, 0, stream>>>(mh2, W3T, b3, out);
}